// Round 13
// baseline (147.509 us; speedup 1.0000x reference)
//
#include <hip/hip_runtime.h>
#include <hip/hip_bf16.h>
#include <stdint.h>

typedef __hip_bfloat16 bf16;
typedef __attribute__((ext_vector_type(8))) short short8;
typedef __attribute__((ext_vector_type(4))) float f32x4;
typedef __attribute__((ext_vector_type(16))) float f32x16;

#define MFMA16(A, B, C) __builtin_amdgcn_mfma_f32_16x16x32_bf16(A, B, C, 0, 0, 0)
#define MFMA32(A, B, C) __builtin_amdgcn_mfma_f32_32x32x16_bf16(A, B, C, 0, 0, 0)

// ---- constants ----
#define SB 2
#define SS 2048
#define SD 768
#define SH 12
#define SM (SB*SS)            // 4096 rows
#define BHSD (SB*SH*SS*64)    // 3145728 elems per Q/K/V
// (1/sqrt(64)) * log2(e) folded into Q at projection time -> attn works in exp2 domain
#define QSCALE 0.18033688011112042f

__device__ __forceinline__ void gload_lds16(const bf16* g, bf16* l) {
    __builtin_amdgcn_global_load_lds(
        (const __attribute__((address_space(1))) void*)(g),
        (__attribute__((address_space(3))) void*)(l),
        16, 0, 0);
}

// f32 pair -> packed bf16 (lo=a, hi=b)
__device__ __forceinline__ int cvtpk(float a, float b) {
    int r;
    asm("v_cvt_pk_bf16_f32 %0, %1, %2" : "=v"(r) : "v"(a), "v"(b));
    return r;
}
// a's lanes 32-63 <-> b's lanes 0-31
__device__ __forceinline__ void plswap(int& a, int& b) {
    asm("v_permlane32_swap_b32 %0, %1" : "+v"(a), "+v"(b));
}

// ---- fused f32 -> bf16 convert for x + 4 weights ----
__global__ void cvt_all(const float4* __restrict__ x,  const float4* __restrict__ w0,
                        const float4* __restrict__ w1, const float4* __restrict__ w2,
                        const float4* __restrict__ w3,
                        uint64_t* __restrict__ xb, uint64_t* __restrict__ wqkv,
                        uint64_t* __restrict__ wob) {
    int bid = blockIdx.x;
    const float4* s; uint64_t* d; int base;
    if (bid < 3072) { s = x; d = xb; base = bid << 8; }
    else {
        int t = bid - 3072, seg = t / 576, li = t - seg * 576;
        s = (seg == 0) ? w0 : (seg == 1) ? w1 : (seg == 2) ? w2 : w3;
        d = (seg < 3) ? (wqkv + seg * 147456) : wob;
        base = li << 8;
    }
    int i = base + threadIdx.x;
    float4 v = s[i];
    union { bf16 h[4]; uint64_t u; } p;
    p.h[0] = __float2bfloat16(v.x);
    p.h[1] = __float2bfloat16(v.y);
    p.h[2] = __float2bfloat16(v.z);
    p.h[3] = __float2bfloat16(v.w);
    d[i] = p.u;
}

// ---- MFMA GEMM: Y = A[M,K] @ Bw[N,K]^T, 128x128 tile, BK=64 ----
template<int EPI>
__global__ __launch_bounds__(256) void gemm_bt(const bf16* __restrict__ A,
                                               const bf16* __restrict__ Bw,
                                               void* __restrict__ Out,
                                               int K) {
    __shared__ bf16 lA[128 * 64];
    __shared__ bf16 lB[128 * 64];
    const int tid  = threadIdx.x;
    const int lane = tid & 63;
    const int wid  = tid >> 6;
    const int wr = wid >> 1, wc = wid & 1;
    const int m0 = blockIdx.y * 128, n0 = blockIdx.x * 128;
    const int g = lane >> 4, l15 = lane & 15;
    const int srow = lane >> 3, slot = lane & 7;

    f32x4 acc[4][4] = {};

    for (int kt = 0; kt < K; kt += 64) {
        __syncthreads();
        #pragma unroll
        for (int p = 0; p < 4; ++p) {
            int c = wid * 4 + p;
            int row = c * 8 + srow;
            int colsw = (slot ^ (row & 7)) * 8;
            gload_lds16(A  + (m0 + row) * K + kt + colsw, &lA[c * 512]);
            gload_lds16(Bw + (n0 + row) * K + kt + colsw, &lB[c * 512]);
        }
        __syncthreads();
        #pragma unroll
        for (int ks = 0; ks < 2; ++ks) {
            short8 af[4], bfv[4];
            #pragma unroll
            for (int m = 0; m < 4; ++m) {
                int row = wr * 64 + m * 16 + l15;
                int idx = row * 64 + (((ks * 4 + g) ^ (row & 7)) * 8);
                af[m] = *reinterpret_cast<const short8*>(&lA[idx]);
            }
            #pragma unroll
            for (int n = 0; n < 4; ++n) {
                int row = wc * 64 + n * 16 + l15;
                int idx = row * 64 + (((ks * 4 + g) ^ (row & 7)) * 8);
                bfv[n] = *reinterpret_cast<const short8*>(&lB[idx]);
            }
            #pragma unroll
            for (int m = 0; m < 4; ++m)
                #pragma unroll
                for (int n = 0; n < 4; ++n)
                    acc[m][n] = MFMA16(af[m], bfv[n], acc[m][n]);
        }
    }

    #pragma unroll
    for (int m = 0; m < 4; ++m) {
        #pragma unroll
        for (int n = 0; n < 4; ++n) {
            int col = n0 + wc * 64 + n * 16 + l15;
            #pragma unroll
            for (int r = 0; r < 4; ++r) {
                int row = m0 + wr * 64 + m * 16 + g * 4 + r;
                float v = acc[m][n][r];
                if constexpr (EPI == 0) {
                    int which = (col >= 1536) ? 2 : (col >= 768 ? 1 : 0);
                    int e = col - which * 768;
                    int h = e >> 6, d = e & 63;
                    int b = row >> 11, s = row & 2047;
                    int bh = b * SH + h;
                    bf16* dst = (bf16*)Out;
                    int idx;
                    if (which == 2) idx = 2 * BHSD + (bh * 64 + d) * SS + s;   // V^T [bh][dk][s]
                    else            idx = which * BHSD + (bh * SS + s) * 64 + d;
                    if (which == 0) v *= QSCALE;
                    dst[idx] = __float2bfloat16(v);
                } else {
                    ((float*)Out)[row * SD + col] = v;
                }
            }
        }
    }
}

// ---- split-K flash attention: 3840 uniform units, 4 per 256-thread block ----
// H1 test vs R12: identical per-wave body/indexing, but 4 INDEPENDENT units
// per 4-wave workgroup (no barriers, no LDS) so waves must spread across the
// CU's 4 SIMDs. 960 blocks = 3.75/CU = 15 waves/CU available.
__global__ __launch_bounds__(256) void attn_kernel(const bf16* __restrict__ Qb,
                                                   const bf16* __restrict__ Kb,
                                                   const bf16* __restrict__ Vtb,
                                                   float* __restrict__ Op,
                                                   float* __restrict__ lp) {
    const int bid = blockIdx.x;                       // 0..959
    const int xcd = bid & 7, lb = bid >> 3;           // lb 0..119
    const int g40 = lb / 40;                          // 0..2
    const int bh = xcd * 3 + g40;
    const int u = (lb - g40 * 40) * 4 + (threadIdx.x >> 6);   // 0..159

    // decode unit -> (j, ck):  chunks per q-tile = (j>>4)+1
    int j, ck;
    if (u < 16)      { j = u;                 ck = 0; }
    else if (u < 48) { int t = u - 16; j = 16 + (t >> 1); ck = t & 1; }
    else if (u < 96) { int t = u - 48; int q3 = t / 3; j = 32 + q3; ck = t - 3 * q3; }
    else             { int t = u - 96; j = 48 + (t >> 2); ck = t & 3; }

    const int lane = threadIdx.x & 63;
    const int l31 = lane & 31, hi = (lane >> 5) & 1;

    const bf16* Qh = Qb + bh * SS * 64;
    const bf16* Kh = Kb + bh * SS * 64;
    const bf16* Vh = Vtb + bh * 64 * SS;

    const int qself = j * 32 + l31;
    short8 qf[4];
    #pragma unroll
    for (int ks = 0; ks < 4; ++ks)
        qf[ks] = *reinterpret_cast<const short8*>(Qh + qself * 64 + ks * 16 + hi * 8);

    f32x16 oacc[2];
    #pragma unroll
    for (int n = 0; n < 2; ++n)
        #pragma unroll
        for (int r = 0; r < 16; ++r) oacc[n][r] = 0.f;
    float lrow = 0.f;    // per-lane partial for q-row l31

    // per-lane fragment bases (exact MFMA32 operand layouts; R9-verified)
    const bf16* kbase = Kh + l31 * 64 + hi * 8;    // + T*2048 + ks*16
    const bf16* vbase = Vh + l31 * SS + hi * 8;    // + n*65536 + T*32 + ks*16

#define LDG(pp) (*reinterpret_cast<const short8*>(pp))

#define LOADSET2(K00, K01, K02, K03, K10, K11, K12, K13,                     \
                 V00, V01, V02, V03, V10, V11, V12, V13, P) do {             \
    const bf16* kp0_ = kbase + (2 * (P)) * 2048;                             \
    K00 = LDG(kp0_);        K01 = LDG(kp0_ + 16);                            \
    K02 = LDG(kp0_ + 32);   K03 = LDG(kp0_ + 48);                            \
    K10 = LDG(kp0_ + 2048); K11 = LDG(kp0_ + 2064);                          \
    K12 = LDG(kp0_ + 2080); K13 = LDG(kp0_ + 2096);                          \
    const bf16* vp0_ = vbase + (2 * (P)) * 32;                               \
    V00 = LDG(vp0_);             V01 = LDG(vp0_ + 16);                       \
    V02 = LDG(vp0_ + 65536);     V03 = LDG(vp0_ + 65536 + 16);               \
    V10 = LDG(vp0_ + 32);        V11 = LDG(vp0_ + 48);                       \
    V12 = LDG(vp0_ + 65536 + 32);V13 = LDG(vp0_ + 65536 + 48);               \
} while (0)

#define TILE2_BODY(K00, K01, K02, K03, K10, K11, K12, K13,                   \
                   V00, V01, V02, V03, V10, V11, V12, V13, PT) do {          \
    const int T0_ = 2 * (PT), T1_ = T0_ + 1;                                 \
    f32x16 s0_, s1_;                                                         \
    _Pragma("unroll")                                                        \
    for (int r = 0; r < 16; ++r) { s0_[r] = 0.f; s1_[r] = 0.f; }             \
    __builtin_amdgcn_s_setprio(1);                                           \
    s0_ = MFMA32(K00, qf[0], s0_);  s1_ = MFMA32(K10, qf[0], s1_);           \
    s0_ = MFMA32(K01, qf[1], s0_);  s1_ = MFMA32(K11, qf[1], s1_);           \
    s0_ = MFMA32(K02, qf[2], s0_);  s1_ = MFMA32(K12, qf[2], s1_);           \
    s0_ = MFMA32(K03, qf[3], s0_);  s1_ = MFMA32(K13, qf[3], s1_);           \
    __builtin_amdgcn_s_setprio(0);                                           \
    if (T0_ == j) {                                                          \
        _Pragma("unroll")                                                    \
        for (int r = 0; r < 16; ++r) {                                       \
            int kvrow = (r & 3) + 8 * (r >> 2) + 4 * hi;                     \
            if (kvrow > l31) s0_[r] = -1e30f;                                \
        }                                                                    \
    }                                                                        \
    if (T1_ == j) {                                                          \
        _Pragma("unroll")                                                    \
        for (int r = 0; r < 16; ++r) {                                       \
            int kvrow = (r & 3) + 8 * (r >> 2) + 4 * hi;                     \
            if (kvrow > l31) s1_[r] = -1e30f;                                \
        }                                                                    \
    } else if (T1_ > j) {                                                    \
        _Pragma("unroll")                                                    \
        for (int r = 0; r < 16; ++r) s1_[r] = -1e30f;                        \
    }                                                                        \
    /* P' = exp2(S) directly: shift cancels in O'/l' (R11-verified) */       \
    _Pragma("unroll")                                                        \
    for (int r = 0; r < 16; ++r) {                                           \
        s0_[r] = exp2f(s0_[r]);                                              \
        s1_[r] = exp2f(s1_[r]);                                              \
    }                                                                        \
    float w0 = ((s0_[0] + s0_[1]) + (s0_[2] + s0_[3]))                       \
             + ((s0_[4] + s0_[5]) + (s0_[6] + s0_[7]));                      \
    float w1 = ((s0_[8] + s0_[9]) + (s0_[10] + s0_[11]))                     \
             + ((s0_[12] + s0_[13]) + (s0_[14] + s0_[15]));                  \
    float w2 = ((s1_[0] + s1_[1]) + (s1_[2] + s1_[3]))                       \
             + ((s1_[4] + s1_[5]) + (s1_[6] + s1_[7]));                      \
    float w3 = ((s1_[8] + s1_[9]) + (s1_[10] + s1_[11]))                     \
             + ((s1_[12] + s1_[13]) + (s1_[14] + s1_[15]));                  \
    lrow += (w0 + w1) + (w2 + w3);                                           \
    int a0 = cvtpk(s0_[0],  s0_[1]),  a1 = cvtpk(s0_[2],  s0_[3]);           \
    int b0 = cvtpk(s0_[4],  s0_[5]),  b1 = cvtpk(s0_[6],  s0_[7]);           \
    plswap(a0, b0); plswap(a1, b1);                                          \
    int a2 = cvtpk(s0_[8],  s0_[9]),  a3 = cvtpk(s0_[10], s0_[11]);          \
    int b2 = cvtpk(s0_[12], s0_[13]), b3 = cvtpk(s0_[14], s0_[15]);          \
    plswap(a2, b2); plswap(a3, b3);                                          \
    int c0 = cvtpk(s1_[0],  s1_[1]),  c1 = cvtpk(s1_[2],  s1_[3]);           \
    int d0 = cvtpk(s1_[4],  s1_[5]),  d1 = cvtpk(s1_[6],  s1_[7]);           \
    plswap(c0, d0); plswap(c1, d1);                                          \
    int c2 = cvtpk(s1_[8],  s1_[9]),  c3 = cvtpk(s1_[10], s1_[11]);          \
    int d2 = cvtpk(s1_[12], s1_[13]), d3 = cvtpk(s1_[14], s1_[15]);          \
    plswap(c2, d2); plswap(c3, d3);                                          \
    union { int wd[4]; short8 s8; } u0_, u1_, u2_, u3_;                      \
    u0_.wd[0] = a0; u0_.wd[1] = a1; u0_.wd[2] = b0; u0_.wd[3] = b1;          \
    u1_.wd[0] = a2; u1_.wd[1] = a3; u1_.wd[2] = b2; u1_.wd[3] = b3;          \
    u2_.wd[0] = c0; u2_.wd[1] = c1; u2_.wd[2] = d0; u2_.wd[3] = d1;          \
    u3_.wd[0] = c2; u3_.wd[1] = c3; u3_.wd[2] = d2; u3_.wd[3] = d3;          \
    __builtin_amdgcn_s_setprio(1);                                           \
    oacc[0] = MFMA32(u0_.s8, V00, oacc[0]);                                  \
    oacc[1] = MFMA32(u0_.s8, V02, oacc[1]);                                  \
    oacc[0] = MFMA32(u1_.s8, V01, oacc[0]);                                  \
    oacc[1] = MFMA32(u1_.s8, V03, oacc[1]);                                  \
    oacc[0] = MFMA32(u2_.s8, V10, oacc[0]);                                  \
    oacc[1] = MFMA32(u2_.s8, V12, oacc[1]);                                  \
    oacc[0] = MFMA32(u3_.s8, V11, oacc[0]);                                  \
    oacc[1] = MFMA32(u3_.s8, V13, oacc[1]);                                  \
    __builtin_amdgcn_s_setprio(0);                                           \
} while (0)

    short8 kA00, kA01, kA02, kA03, kA10, kA11, kA12, kA13;
    short8 vA00, vA01, vA02, vA03, vA10, vA11, vA12, vA13;
    short8 kB00, kB01, kB02, kB03, kB10, kB11, kB12, kB13;
    short8 vB00, vB01, vB02, vB03, vB10, vB11, vB12, vB13;

    const int jp = j >> 1;              // last pair-tile of this q-tile
    const int p0 = ck * 8;              // unit's pair range [p0, pe]
    const int pe = (jp < p0 + 7) ? jp : (p0 + 7);

    LOADSET2(kA00,kA01,kA02,kA03,kA10,kA11,kA12,kA13,
             vA00,vA01,vA02,vA03,vA10,vA11,vA12,vA13, p0);
    LOADSET2(kB00,kB01,kB02,kB03,kB10,kB11,kB12,kB13,
             vB00,vB01,vB02,vB03,vB10,vB11,vB12,vB13, p0 + 1);   // benign overfetch

    int pt = p0;
    for (;;) {
        TILE2_BODY(kA00,kA01,kA02,kA03,kA10,kA11,kA12,kA13,
                   vA00,vA01,vA02,vA03,vA10,vA11,vA12,vA13, pt);
        LOADSET2(kA00,kA01,kA02,kA03,kA10,kA11,kA12,kA13,
                 vA00,vA01,vA02,vA03,vA10,vA11,vA12,vA13, pt + 2);
        ++pt;
        if (pt > pe) break;
        TILE2_BODY(kB00,kB01,kB02,kB03,kB10,kB11,kB12,kB13,
                   vB00,vB01,vB02,vB03,vB10,vB11,vB12,vB13, pt);
        LOADSET2(kB00,kB01,kB02,kB03,kB10,kB11,kB12,kB13,
                 vB00,vB01,vB02,vB03,vB10,vB11,vB12,vB13, pt + 2);
        ++pt;
        if (pt > pe) break;
    }

    // ---- epilogue: atomically accumulate partial (O', l') ----
    const int qrow0 = bh * SS + j * 32;
    atomicAdd(&lp[qrow0 + l31], lrow);
    #pragma unroll
    for (int n = 0; n < 2; ++n) {
        #pragma unroll
        for (int r = 0; r < 16; ++r) {
            int q = (r & 3) + 8 * (r >> 2) + 4 * hi;
            int d = n * 32 + l31;
            atomicAdd(&Op[(qrow0 + q) * 64 + d], oacc[n][r]);
        }
    }
}

// ---- normalize: AO[b,s,h*64+d] = Op[bh,s,d] / lp[bh,s] ----
__global__ __launch_bounds__(256) void norm_kernel(const float* __restrict__ Op,
                                                   const float* __restrict__ lp,
                                                   bf16* __restrict__ AO) {
    int idx = blockIdx.x * 256 + threadIdx.x;     // 0 .. 3145727
    int d = idx & 63, srow = idx >> 6;            // srow = bh*2048 + s
    int bh = srow >> 11, s = srow & 2047;
    int b = bh / SH, h = bh - b * SH;
    float v = Op[idx] / lp[srow];
    AO[(b * SS + s) * SD + h * 64 + d] = __float2bfloat16(v);
}

extern "C" void kernel_launch(void* const* d_in, const int* in_sizes, int n_in,
                              void* d_out, int out_size, void* d_ws, size_t ws_size,
                              hipStream_t stream) {
    const float* x  = (const float*)d_in[0];
    const float* wq = (const float*)d_in[1];
    const float* wk = (const float*)d_in[2];
    const float* wv = (const float*)d_in[3];
    const float* wo = (const float*)d_in[4];
    float* out = (float*)d_out;

    bf16* xb   = (bf16*)d_ws;              // 3,145,728 bf16 (reused as ao later)
    bf16* wqkv = xb + SM * SD;
    bf16* wob  = wqkv + 3 * SD * SD;
    bf16* qkv  = wob + SD * SD;            // Q, K, V^T
    float* Op  = (float*)(qkv + 3 * BHSD); // 3,145,728 f32 partial O'
    float* lp  = Op + 3145728;             // 49,152 f32
    bf16* ao   = xb;                       // xb is dead after gemm<0>

    // zero the split-K accumulators (Op and lp are contiguous)
    hipMemsetAsync(Op, 0, (3145728 + SB * SH * SS) * sizeof(float), stream);

    cvt_all<<<3072 + 4 * 576, 256, 0, stream>>>(
        (const float4*)x, (const float4*)wq, (const float4*)wk,
        (const float4*)wv, (const float4*)wo,
        (uint64_t*)xb, (uint64_t*)wqkv, (uint64_t*)wob);

    gemm_bt<0><<<dim3(2304 / 128, SM / 128), 256, 0, stream>>>(xb, wqkv, (void*)qkv, SD);
    attn_kernel<<<960, 256, 0, stream>>>(qkv, qkv + BHSD, qkv + 2 * BHSD, Op, lp);
    norm_kernel<<<3145728 / 256, 256, 0, stream>>>(Op, lp, ao);
    gemm_bt<1><<<dim3(SD / 128, SM / 128), 256, 0, stream>>>(ao, wob, (void*)out, SD);
}

// Round 14
// 120.782 us; speedup vs baseline: 1.2213x; 1.2213x over previous
//
#include <hip/hip_runtime.h>
#include <hip/hip_bf16.h>
#include <stdint.h>

typedef __hip_bfloat16 bf16;
typedef __attribute__((ext_vector_type(8))) short short8;
typedef __attribute__((ext_vector_type(4))) float f32x4;
typedef __attribute__((ext_vector_type(16))) float f32x16;

#define MFMA16(A, B, C) __builtin_amdgcn_mfma_f32_16x16x32_bf16(A, B, C, 0, 0, 0)
#define MFMA32(A, B, C) __builtin_amdgcn_mfma_f32_32x32x16_bf16(A, B, C, 0, 0, 0)

// ---- constants ----
#define SB 2
#define SS 2048
#define SD 768
#define SH 12
#define SM (SB*SS)            // 4096 rows
#define BHSD (SB*SH*SS*64)    // 3145728 elems per Q/K/V
// (1/sqrt(64)) * log2(e) folded into Q at projection time -> attn works in exp2 domain
#define QSCALE 0.18033688011112042f

__device__ __forceinline__ void gload_lds16(const bf16* g, bf16* l) {
    __builtin_amdgcn_global_load_lds(
        (const __attribute__((address_space(1))) void*)(g),
        (__attribute__((address_space(3))) void*)(l),
        16, 0, 0);
}

#define BARSYNC() do { \
    asm volatile("s_waitcnt vmcnt(0)" ::: "memory"); \
    __builtin_amdgcn_s_barrier(); \
    __builtin_amdgcn_sched_barrier(0); \
} while (0)

// f32 pair -> packed bf16 (lo=a, hi=b)
__device__ __forceinline__ int cvtpk(float a, float b) {
    int r;
    asm("v_cvt_pk_bf16_f32 %0, %1, %2" : "=v"(r) : "v"(a), "v"(b));
    return r;
}
// a's lanes 32-63 <-> b's lanes 0-31
__device__ __forceinline__ void plswap(int& a, int& b) {
    asm("v_permlane32_swap_b32 %0, %1" : "+v"(a), "+v"(b));
}

// ---- fused f32 -> bf16 convert for x + 4 weights ----
__global__ void cvt_all(const float4* __restrict__ x,  const float4* __restrict__ w0,
                        const float4* __restrict__ w1, const float4* __restrict__ w2,
                        const float4* __restrict__ w3,
                        uint64_t* __restrict__ xb, uint64_t* __restrict__ wqkv,
                        uint64_t* __restrict__ wob) {
    int bid = blockIdx.x;
    const float4* s; uint64_t* d; int base;
    if (bid < 3072) { s = x; d = xb; base = bid << 8; }
    else {
        int t = bid - 3072, seg = t / 576, li = t - seg * 576;
        s = (seg == 0) ? w0 : (seg == 1) ? w1 : (seg == 2) ? w2 : w3;
        d = (seg < 3) ? (wqkv + seg * 147456) : wob;
        base = li << 8;
    }
    int i = base + threadIdx.x;
    float4 v = s[i];
    union { bf16 h[4]; uint64_t u; } p;
    p.h[0] = __float2bfloat16(v.x);
    p.h[1] = __float2bfloat16(v.y);
    p.h[2] = __float2bfloat16(v.z);
    p.h[3] = __float2bfloat16(v.w);
    d[i] = p.u;
}

// ---- MFMA GEMM: Y = A[M,K] @ Bw[N,K]^T, 128x128 tile, BK=64 ----
template<int EPI>
__global__ __launch_bounds__(256) void gemm_bt(const bf16* __restrict__ A,
                                               const bf16* __restrict__ Bw,
                                               void* __restrict__ Out,
                                               int K) {
    __shared__ bf16 lA[128 * 64];
    __shared__ bf16 lB[128 * 64];
    const int tid  = threadIdx.x;
    const int lane = tid & 63;
    const int wid  = tid >> 6;
    const int wr = wid >> 1, wc = wid & 1;
    const int m0 = blockIdx.y * 128, n0 = blockIdx.x * 128;
    const int g = lane >> 4, l15 = lane & 15;
    const int srow = lane >> 3, slot = lane & 7;

    f32x4 acc[4][4] = {};

    for (int kt = 0; kt < K; kt += 64) {
        __syncthreads();
        #pragma unroll
        for (int p = 0; p < 4; ++p) {
            int c = wid * 4 + p;
            int row = c * 8 + srow;
            int colsw = (slot ^ (row & 7)) * 8;
            gload_lds16(A  + (m0 + row) * K + kt + colsw, &lA[c * 512]);
            gload_lds16(Bw + (n0 + row) * K + kt + colsw, &lB[c * 512]);
        }
        __syncthreads();
        #pragma unroll
        for (int ks = 0; ks < 2; ++ks) {
            short8 af[4], bfv[4];
            #pragma unroll
            for (int m = 0; m < 4; ++m) {
                int row = wr * 64 + m * 16 + l15;
                int idx = row * 64 + (((ks * 4 + g) ^ (row & 7)) * 8);
                af[m] = *reinterpret_cast<const short8*>(&lA[idx]);
            }
            #pragma unroll
            for (int n = 0; n < 4; ++n) {
                int row = wc * 64 + n * 16 + l15;
                int idx = row * 64 + (((ks * 4 + g) ^ (row & 7)) * 8);
                bfv[n] = *reinterpret_cast<const short8*>(&lB[idx]);
            }
            #pragma unroll
            for (int m = 0; m < 4; ++m)
                #pragma unroll
                for (int n = 0; n < 4; ++n)
                    acc[m][n] = MFMA16(af[m], bfv[n], acc[m][n]);
        }
    }

    #pragma unroll
    for (int m = 0; m < 4; ++m) {
        #pragma unroll
        for (int n = 0; n < 4; ++n) {
            int col = n0 + wc * 64 + n * 16 + l15;
            #pragma unroll
            for (int r = 0; r < 4; ++r) {
                int row = m0 + wr * 64 + m * 16 + g * 4 + r;
                float v = acc[m][n][r];
                if constexpr (EPI == 0) {
                    int which = (col >= 1536) ? 2 : (col >= 768 ? 1 : 0);
                    int e = col - which * 768;
                    int h = e >> 6, d = e & 63;
                    int b = row >> 11, s = row & 2047;
                    int bh = b * SH + h;
                    bf16* dst = (bf16*)Out;
                    int idx;
                    if (which == 2) idx = 2 * BHSD + (bh * 64 + d) * SS + s;   // V^T [bh][dk][s]
                    else            idx = which * BHSD + (bh * SS + s) * 64 + d;
                    if (which == 0) v *= QSCALE;
                    dst[idx] = __float2bfloat16(v);
                } else {
                    ((float*)Out)[row * SD + col] = v;
                }
            }
        }
    }
}

// ---- flash attention: shared-LDS 4-wave blocks, split-K, exp2-direct ----
// Unit = (bh, q-group of 4 q-tiles = 128 rows, kv-chunk of <=8 pair-steps).
// All 4 waves SHARE the staged K/V tiles (4x LDS reuse -> L2 traffic /4,
// which was the R9-R13 wall); wave w owns q-tile j = qg*4+w. exp2-direct
// (R11) keeps waves independent; atomic f32 epilogue (R12) merges chunks.
// STAGE/swizzle/read formulas are R6-verified verbatim.
__global__ __launch_bounds__(256) void attn_kernel(const bf16* __restrict__ Qb,
                                                   const bf16* __restrict__ Kb,
                                                   const bf16* __restrict__ Vtb,
                                                   float* __restrict__ Op,
                                                   float* __restrict__ lp) {
    __shared__ bf16 lK[2][4096];   // [kv 64][d 64], swizzled
    __shared__ bf16 lV[2][4096];   // [d 64][kv 64], swizzled

    const int bid = blockIdx.x;              // 0..959
    const int xcd = bid & 7, li = bid >> 3;  // li 0..119
    const int g40 = li / 40;                 // 0..2
    const int bh = xcd * 3 + g40;
    const int u = li - g40 * 40;             // 0..39

    // decode unit -> (qg, ck); chunks per group = ceil((2qg+2)/8)
    int qg, ck;
    if (u < 4)       { qg = u;                           ck = 0; }
    else if (u < 12) { int t = u - 4;  qg = 4 + (t >> 1);  ck = t & 1; }
    else if (u < 24) { int t = u - 12; int q3 = t / 3; qg = 8 + q3; ck = t - 3 * q3; }
    else             { int t = u - 24; qg = 12 + (t >> 2); ck = t & 3; }

    const int tid = threadIdx.x, lane = tid & 63, w = tid >> 6;
    const int l31 = lane & 31, hi = lane >> 5;
    const int srow = lane >> 3, slot = lane & 7;

    const int j  = qg * 4 + w;            // this wave's q-tile (32 rows)
    const int jp = 2 * qg + (w >> 1);     // wave's last pair-step
    const int p0 = ck * 8;
    const int pe_ = 2 * qg + 1;
    const int pe = (p0 + 7 < pe_) ? (p0 + 7) : pe_;   // block chunk end

    const bf16* Qh = Qb + bh * SS * 64;
    const bf16* Kh = Kb + bh * SS * 64;
    const bf16* Vh = Vtb + bh * 64 * SS;

    const int qself = j * 32 + l31;
    short8 qf[4];
    #pragma unroll
    for (int ks = 0; ks < 4; ++ks)
        qf[ks] = *reinterpret_cast<const short8*>(Qh + qself * 64 + ks * 16 + hi * 8);

    f32x16 oacc[2];
    #pragma unroll
    for (int n = 0; n < 2; ++n)
        #pragma unroll
        for (int r = 0; r < 16; ++r) oacc[n][r] = 0.f;
    float lrow = 0.f;

    // R6-verified cooperative staging: 4 waves cover 8 chunks of K + V
    auto STAGE = [&](int buf, int kt) {
        #pragma unroll
        for (int p = 0; p < 2; ++p) {
            int c = w * 2 + p;                   // chunk 0..7, 8 rows each
            int row = c * 8 + srow;
            int colsw = (slot ^ (row & 7)) * 8;
            gload_lds16(Kh + (kt * 64 + row) * 64 + colsw, &lK[buf][c * 512]);
            gload_lds16(Vh + row * SS + kt * 64 + colsw, &lV[buf][c * 512]);
        }
    };

    STAGE(0, p0);
    BARSYNC();

    int cur = 0;
    for (int pt = p0; pt <= pe; ++pt) {
        if (pt < pe) STAGE(cur ^ 1, pt + 1);

        if (pt <= jp) {
            const int T0 = 2 * pt, T1 = T0 + 1;
            f32x16 s0_, s1_;
            #pragma unroll
            for (int r = 0; r < 16; ++r) { s0_[r] = 0.f; s1_[r] = 0.f; }

            __builtin_amdgcn_s_setprio(1);
            #pragma unroll
            for (int ks = 0; ks < 4; ++ks) {
                int row0 = l31;
                int idx0 = row0 * 64 + (((2 * ks + hi) ^ (row0 & 7)) * 8);
                short8 kf0 = *reinterpret_cast<const short8*>(&lK[cur][idx0]);
                s0_ = MFMA32(kf0, qf[ks], s0_);
                int row1 = 32 + l31;
                int idx1 = row1 * 64 + (((2 * ks + hi) ^ (row1 & 7)) * 8);
                short8 kf1 = *reinterpret_cast<const short8*>(&lK[cur][idx1]);
                s1_ = MFMA32(kf1, qf[ks], s1_);
            }
            __builtin_amdgcn_s_setprio(0);

            if (T0 == j) {
                #pragma unroll
                for (int r = 0; r < 16; ++r) {
                    int kvrow = (r & 3) + 8 * (r >> 2) + 4 * hi;
                    if (kvrow > l31) s0_[r] = -1e30f;
                }
            }
            if (T1 == j) {
                #pragma unroll
                for (int r = 0; r < 16; ++r) {
                    int kvrow = (r & 3) + 8 * (r >> 2) + 4 * hi;
                    if (kvrow > l31) s1_[r] = -1e30f;
                }
            } else if (T1 > j) {
                #pragma unroll
                for (int r = 0; r < 16; ++r) s1_[r] = -1e30f;
            }

            // exp2-direct (R11): shift cancels in O'/l'
            #pragma unroll
            for (int r = 0; r < 16; ++r) {
                s0_[r] = exp2f(s0_[r]);
                s1_[r] = exp2f(s1_[r]);
            }
            float w0 = ((s0_[0] + s0_[1]) + (s0_[2] + s0_[3]))
                     + ((s0_[4] + s0_[5]) + (s0_[6] + s0_[7]));
            float w1 = ((s0_[8] + s0_[9]) + (s0_[10] + s0_[11]))
                     + ((s0_[12] + s0_[13]) + (s0_[14] + s0_[15]));
            float w2 = ((s1_[0] + s1_[1]) + (s1_[2] + s1_[3]))
                     + ((s1_[4] + s1_[5]) + (s1_[6] + s1_[7]));
            float w3 = ((s1_[8] + s1_[9]) + (s1_[10] + s1_[11]))
                     + ((s1_[12] + s1_[13]) + (s1_[14] + s1_[15]));
            lrow += (w0 + w1) + (w2 + w3);

            // P -> bf16 fragments (R11-verified cvtpk + plswap)
            int a0 = cvtpk(s0_[0],  s0_[1]),  a1 = cvtpk(s0_[2],  s0_[3]);
            int b0 = cvtpk(s0_[4],  s0_[5]),  b1 = cvtpk(s0_[6],  s0_[7]);
            plswap(a0, b0); plswap(a1, b1);
            int a2 = cvtpk(s0_[8],  s0_[9]),  a3 = cvtpk(s0_[10], s0_[11]);
            int b2 = cvtpk(s0_[12], s0_[13]), b3 = cvtpk(s0_[14], s0_[15]);
            plswap(a2, b2); plswap(a3, b3);
            int c0 = cvtpk(s1_[0],  s1_[1]),  c1 = cvtpk(s1_[2],  s1_[3]);
            int d0 = cvtpk(s1_[4],  s1_[5]),  d1 = cvtpk(s1_[6],  s1_[7]);
            plswap(c0, d0); plswap(c1, d1);
            int c2 = cvtpk(s1_[8],  s1_[9]),  c3 = cvtpk(s1_[10], s1_[11]);
            int d2 = cvtpk(s1_[12], s1_[13]), d3 = cvtpk(s1_[14], s1_[15]);
            plswap(c2, d2); plswap(c3, d3);
            union { int wd[4]; short8 s8; } u0_, u1_, u2_, u3_;
            u0_.wd[0] = a0; u0_.wd[1] = a1; u0_.wd[2] = b0; u0_.wd[3] = b1;
            u1_.wd[0] = a2; u1_.wd[1] = a3; u1_.wd[2] = b2; u1_.wd[3] = b3;
            u2_.wd[0] = c0; u2_.wd[1] = c1; u2_.wd[2] = d0; u2_.wd[3] = d1;
            u3_.wd[0] = c2; u3_.wd[1] = c3; u3_.wd[2] = d2; u3_.wd[3] = d3;

            // O += P @ V from LDS (R6-verified idx: slot = 4t + 2ks + hi)
            __builtin_amdgcn_s_setprio(1);
            #pragma unroll
            for (int n = 0; n < 2; ++n) {
                int rowv = n * 32 + l31;
                int base = rowv * 64;
                int sw = rowv & 7;
                short8 vf0 = *reinterpret_cast<const short8*>(&lV[cur][base + (((0 + hi) ^ sw) * 8)]);
                oacc[n] = MFMA32(u0_.s8, vf0, oacc[n]);
                short8 vf1 = *reinterpret_cast<const short8*>(&lV[cur][base + (((2 + hi) ^ sw) * 8)]);
                oacc[n] = MFMA32(u1_.s8, vf1, oacc[n]);
                short8 vf2 = *reinterpret_cast<const short8*>(&lV[cur][base + (((4 + hi) ^ sw) * 8)]);
                oacc[n] = MFMA32(u2_.s8, vf2, oacc[n]);
                short8 vf3 = *reinterpret_cast<const short8*>(&lV[cur][base + (((6 + hi) ^ sw) * 8)]);
                oacc[n] = MFMA32(u3_.s8, vf3, oacc[n]);
            }
            __builtin_amdgcn_s_setprio(0);
        }

        BARSYNC();
        cur ^= 1;
    }

    // ---- epilogue: atomically accumulate partial (O', l') (R12-verified) ----
    const int qrow0 = bh * SS + j * 32;
    atomicAdd(&lp[qrow0 + l31], lrow);
    #pragma unroll
    for (int n = 0; n < 2; ++n) {
        #pragma unroll
        for (int r = 0; r < 16; ++r) {
            int q = (r & 3) + 8 * (r >> 2) + 4 * hi;
            int d = n * 32 + l31;
            atomicAdd(&Op[(qrow0 + q) * 64 + d], oacc[n][r]);
        }
    }
}

// ---- normalize: AO[b,s,h*64+d] = Op[bh,s,d] / lp[bh,s] ----
__global__ __launch_bounds__(256) void norm_kernel(const float* __restrict__ Op,
                                                   const float* __restrict__ lp,
                                                   bf16* __restrict__ AO) {
    int idx = blockIdx.x * 256 + threadIdx.x;     // 0 .. 3145727
    int d = idx & 63, srow = idx >> 6;            // srow = bh*2048 + s
    int bh = srow >> 11, s = srow & 2047;
    int b = bh / SH, h = bh - b * SH;
    float v = Op[idx] / lp[srow];
    AO[(b * SS + s) * SD + h * 64 + d] = __float2bfloat16(v);
}

extern "C" void kernel_launch(void* const* d_in, const int* in_sizes, int n_in,
                              void* d_out, int out_size, void* d_ws, size_t ws_size,
                              hipStream_t stream) {
    const float* x  = (const float*)d_in[0];
    const float* wq = (const float*)d_in[1];
    const float* wk = (const float*)d_in[2];
    const float* wv = (const float*)d_in[3];
    const float* wo = (const float*)d_in[4];
    float* out = (float*)d_out;

    bf16* xb   = (bf16*)d_ws;              // reused as ao after gemm<0>
    bf16* wqkv = xb + SM * SD;
    bf16* wob  = wqkv + 3 * SD * SD;
    bf16* qkv  = wob + SD * SD;            // Q, K, V^T
    float* Op  = (float*)(qkv + 3 * BHSD); // 3,145,728 f32 partial O'
    float* lp  = Op + 3145728;             // 49,152 f32
    bf16* ao   = xb;

    hipMemsetAsync(Op, 0, (3145728 + SB * SH * SS) * sizeof(float), stream);

    cvt_all<<<3072 + 4 * 576, 256, 0, stream>>>(
        (const float4*)x, (const float4*)wq, (const float4*)wk,
        (const float4*)wv, (const float4*)wo,
        (uint64_t*)xb, (uint64_t*)wqkv, (uint64_t*)wob);

    gemm_bt<0><<<dim3(2304 / 128, SM / 128), 256, 0, stream>>>(xb, wqkv, (void*)qkv, SD);
    attn_kernel<<<960, 256, 0, stream>>>(qkv, qkv + BHSD, qkv + 2 * BHSD, Op, lp);
    norm_kernel<<<3145728 / 256, 256, 0, stream>>>(Op, lp, ao);
    gemm_bt<1><<<dim3(SD / 128, SM / 128), 256, 0, stream>>>(ao, wob, (void*)out, SD);
}